// Round 18
// baseline (341.953 us; speedup 1.0000x reference)
//
#include <hip/hip_runtime.h>

#define NN 25000
#define NE 400000
#define TT 4
#define NO 32
#define EO 64
#define DD 128
#define OUTD 128
#define EGRID 1250   // 6250 tiles / 1250 blocks = exactly 5 tiles/block
#define REDB (EGRID / 25)   // 50 reduction blocks in k_zphi_fin

// ws offsets (in floats)
#define OFF_Z      0
#define OFF_ASRC   800000
#define OFF_BSRC   825000
#define OFF_BDST   850000
#define OFF_ZPART  875000     // 1250*256 = 320000 floats
#define OFF_C2     1400000
#define OFF_S1X    1800000    // aliased by alpha after k_g2ex
#define OFF_GAMMA  2200000
#define OFF_S2X    2600000
// ---- zero zone [OFF_DEN1, OFF_OFFS) ----
#define OFF_DEN1   3000000
#define OFF_DEN2   3025000
#define OFF_ZPHI   3050000
#define OFF_BETA   3050512
#define OFF_CSRC   3051000
#define OFF_CDST   3151000
#define OFF_DEG    3251000
// ---- end zero zone ----
#define OFF_OFFS   3276000
#define OFF_CURSOR 3301004
#define OFF_EIDX   3326004
#define OFF_HBETA  3726008
#define OFF_U1     6926008
#define OFF_U2     6926072
#define OFF_WT     6926136    // 64*64 bf16 = 2048 floats
#define WS_FLOATS  6928184

#define ZERO_N4    ((OFF_OFFS - OFF_DEN1) / 4)   // 69000 float4s

typedef __attribute__((ext_vector_type(8))) short bf16x8;
typedef __attribute__((ext_vector_type(4))) float f32x4;

__device__ __forceinline__ float lrelu(float x) { return x > 0.f ? x : 0.01f * x; }

__device__ __forceinline__ unsigned short f2b(float x) {
    unsigned u = __float_as_uint(x);
    u += 0x7FFFu + ((u >> 16) & 1u);   // RNE
    return (unsigned short)(u >> 16);
}

// ---- K0: fast zero of the accumulator zone ----
__global__ __launch_bounds__(256) void k_zero(float4* __restrict__ p)
{
    int i = blockIdx.x * 256 + threadIdx.x;
    int stride = gridDim.x * 256;
    for (; i < ZERO_N4; i += stride)
        p[i] = make_float4(0.f, 0.f, 0.f, 0.f);
}

// ---- K1: z = nf @ W_n ; per-node scalars a_src, b_src, b_dst ----
__global__ __launch_bounds__(256) void k_node(const float* __restrict__ nf,
    const float* __restrict__ W_n, const float* __restrict__ w_eattn,
    const float* __restrict__ w_attn, float* __restrict__ z,
    float* __restrict__ a_src, float* __restrict__ b_src, float* __restrict__ b_dst)
{
    __shared__ float Wl[128 * 32];
    __shared__ float nl[8 * 128];
    int tid = threadIdx.x;
    for (int i = tid; i < 128 * 32 / 4; i += 256)
        ((float4*)Wl)[i] = ((const float4*)W_n)[i];
    int nb = blockIdx.x * 8;
    ((float4*)nl)[tid] = ((const float4*)(nf + (size_t)nb * 128))[tid];
    __syncthreads();
    int node = tid >> 5;
    int col = tid & 31;
    float acc = 0.f;
    #pragma unroll 8
    for (int k = 0; k < 128; ++k)
        acc += nl[node * 128 + k] * Wl[k * 32 + col];
    int n = nb + node;
    z[(size_t)n * 32 + col] = acc;
    float va = acc * w_eattn[64 + col];
    float vb = acc * w_attn[col];
    float vc = acc * w_attn[96 + col];
    #pragma unroll
    for (int m = 16; m >= 1; m >>= 1) {
        va += __shfl_xor(va, m);
        vb += __shfl_xor(vb, m);
        vc += __shfl_xor(vc, m);
    }
    if (col == 0) { a_src[n] = va; b_src[n] = vb; b_dst[n] = vc; }
}

// ---- K1b: u1 = W_e @ w_eattn[0:64], u2 = W_e @ w_attn[32:96];
//           Wt[c][k] = bf16(W_e[k][c]) (transposed bf16 copy) ----
__global__ void k_prep(const float* __restrict__ W_e, const float* __restrict__ w_eattn,
                       const float* __restrict__ w_attn, float* __restrict__ u1,
                       float* __restrict__ u2, unsigned short* __restrict__ Wt)
{
    int tid = threadIdx.x;
    if (tid < 64) {
        float s1 = 0.f, s2 = 0.f;
        for (int o = 0; o < 64; ++o) {
            float w = W_e[tid * 64 + o];
            s1 += w * w_eattn[o];
            s2 += w * w_attn[32 + o];
        }
        u1[tid] = s1; u2[tid] = s2;
    }
    for (int i = tid; i < 4096; i += 256) {
        int c = i >> 6, k = i & 63;
        Wt[i] = f2b(W_e[k * 64 + c]);
    }
}

// ---- K2: stream ef: s1x=exp(lrelu(ef·u1+a_src)), c2=ef·u2; den1; deg ----
__global__ __launch_bounds__(256) void k_c12s1(const float* __restrict__ ef,
    const float* __restrict__ u1, const float* __restrict__ u2,
    const float* __restrict__ a_src, const int* __restrict__ src, const int* __restrict__ dst,
    float* __restrict__ c2, float* __restrict__ s1x, float* __restrict__ den1, int* __restrict__ deg)
{
    int lane = threadIdx.x & 15, grp = threadIdx.x >> 4;
    float4 v1 = *(const float4*)&u1[lane * 4];
    float4 v2 = *(const float4*)&u2[lane * 4];
    int estep = gridDim.x * 16;
    for (int e = blockIdx.x * 16 + grp; e < NE; e += estep) {
        float4 x = *(const float4*)&ef[(size_t)e * 64 + lane * 4];
        float d1 = x.x * v1.x + x.y * v1.y + x.z * v1.z + x.w * v1.w;
        float d2 = x.x * v2.x + x.y * v2.y + x.z * v2.z + x.w * v2.w;
        #pragma unroll
        for (int m = 8; m >= 1; m >>= 1) {
            d1 += __shfl_xor(d1, m);
            d2 += __shfl_xor(d2, m);
        }
        if (lane == 0) {
            int s = src[e];
            float ex = expf(lrelu(d1 + a_src[s]));
            s1x[e] = ex;
            c2[e] = d2;
            atomicAdd(&den1[s], ex);
            atomicAdd(&deg[dst[e]], 1);
        }
    }
}

// ---- K4: exclusive prefix scan of deg -> offs, cursor (single block, shfl) ----
__global__ __launch_bounds__(1024) void k_scan(const int* __restrict__ deg,
    int* __restrict__ offs, int* __restrict__ cursor)
{
    __shared__ int wsum[16];
    __shared__ int carry_s;
    int tid = threadIdx.x;
    int lane = tid & 63, wid = tid >> 6;
    if (tid == 0) carry_s = 0;
    __syncthreads();
    for (int base = 0; base < NN; base += 1024) {
        int idx = base + tid;
        int v = (idx < NN) ? deg[idx] : 0;
        int x = v;
        #pragma unroll
        for (int off = 1; off < 64; off <<= 1) {
            int t = __shfl_up(x, off);
            if (lane >= off) x += t;
        }
        if (lane == 63) wsum[wid] = x;
        __syncthreads();
        if (wid == 0) {
            int s = (lane < 16) ? wsum[lane] : 0;
            #pragma unroll
            for (int off = 1; off < 16; off <<= 1) {
                int t = __shfl_up(s, off);
                if (lane >= off) s += t;
            }
            if (lane < 16) wsum[lane] = s;
        }
        __syncthreads();
        int wbase = (wid > 0) ? wsum[wid - 1] : 0;
        int incl = x + wbase;
        int carry = carry_s;
        if (idx < NN) {
            int excl = carry + incl - v;
            offs[idx] = excl;
            cursor[idx] = excl;
        }
        __syncthreads();
        if (tid == 1023) carry_s = carry + incl;
        __syncthreads();
    }
    if (tid == 0) offs[NN] = carry_s;
}

// ---- K5: gamma; ex2 = exp(lrelu(...)); den2 +=; CSR bucket fill ----
__global__ void k_g2ex(const int* __restrict__ src, const int* __restrict__ dst,
    const float* __restrict__ s1x, const float* __restrict__ den1,
    const float* __restrict__ c2, const float* __restrict__ b_src, const float* __restrict__ b_dst,
    float* __restrict__ gamma, float* __restrict__ s2x, float* __restrict__ den2,
    int* __restrict__ cursor, int* __restrict__ eidx)
{
    int e = blockIdx.x * 256 + threadIdx.x;
    if (e >= NE) return;
    int s = src[e], t = dst[e];
    float g = s1x[e] / den1[s];
    gamma[e] = g;
    float ex = expf(lrelu(b_src[s] + g * c2[e] + b_dst[t]));
    s2x[e] = ex;
    atomicAdd(&den2[t], ex);
    int pos = atomicAdd(&cursor[t], 1);
    eidx[pos] = e;
}

// ---- K5b: alpha[e] = s2x/den2[dst]; csrc/cdst per-node-type coefficients ----
__global__ void k_alpha(const int* __restrict__ src, const int* __restrict__ dst,
    const int* __restrict__ ety, const float* __restrict__ s2x, const float* __restrict__ den2,
    float* __restrict__ alpha, float* __restrict__ csrc, float* __restrict__ cdst)
{
    int e = blockIdx.x * 256 + threadIdx.x;
    if (e >= NE) return;
    int t = dst[e];
    int ty = ety[e];
    float al = s2x[e] / den2[t];
    alpha[e] = al;
    atomicAdd(&csrc[src[e] * 4 + ty], al);
    atomicAdd(&cdst[t * 4 + ty], al);
}

// ---- K6: MFMA GEMM (bf16 in, f32 acc) + gamma-scale + e_w write + zphi acc. ----
__global__ __launch_bounds__(256) void k_edge_mfma(const float* __restrict__ ef,
    const unsigned short* __restrict__ Wt, const float* __restrict__ gamma,
    const float* __restrict__ alpha, const int* __restrict__ ety,
    float* __restrict__ ew, float* __restrict__ zpart)
{
    __shared__ float zl[256];
    int tid = threadIdx.x;
    zl[tid] = 0.f;
    int wv = tid >> 6, lane = tid & 63;
    int row16 = lane & 15, grp = lane >> 4;
    int c4 = row16 * 4;
    // B fragments: tile ct -> phys col 4*row16+ct; k = h*32 + grp*8 + i (Wt is [c][k])
    bf16x8 b00 = *(const bf16x8*)&Wt[(c4 + 0) * 64 + 0  + grp * 8];
    bf16x8 b01 = *(const bf16x8*)&Wt[(c4 + 0) * 64 + 32 + grp * 8];
    bf16x8 b10 = *(const bf16x8*)&Wt[(c4 + 1) * 64 + 0  + grp * 8];
    bf16x8 b11 = *(const bf16x8*)&Wt[(c4 + 1) * 64 + 32 + grp * 8];
    bf16x8 b20 = *(const bf16x8*)&Wt[(c4 + 2) * 64 + 0  + grp * 8];
    bf16x8 b21 = *(const bf16x8*)&Wt[(c4 + 2) * 64 + 32 + grp * 8];
    bf16x8 b30 = *(const bf16x8*)&Wt[(c4 + 3) * 64 + 0  + grp * 8];
    bf16x8 b31 = *(const bf16x8*)&Wt[(c4 + 3) * 64 + 32 + grp * 8];
    __syncthreads();
    float4 za0 = make_float4(0, 0, 0, 0), za1 = za0, za2 = za0, za3 = za0;
    for (int tile = blockIdx.x; tile < NE / 64; tile += EGRID) {
        size_t eb = (size_t)tile * 64 + wv * 16;
        f32x4 ac0 = {0.f, 0.f, 0.f, 0.f}, ac1 = ac0, ac2 = ac0, ac3 = ac0;
        const float* ap = &ef[(eb + row16) * 64 + grp * 8];
        {
            float4 x0 = *(const float4*)ap;
            float4 x1 = *(const float4*)(ap + 4);
            bf16x8 a;
            a[0] = (short)f2b(x0.x); a[1] = (short)f2b(x0.y);
            a[2] = (short)f2b(x0.z); a[3] = (short)f2b(x0.w);
            a[4] = (short)f2b(x1.x); a[5] = (short)f2b(x1.y);
            a[6] = (short)f2b(x1.z); a[7] = (short)f2b(x1.w);
            ac0 = __builtin_amdgcn_mfma_f32_16x16x32_bf16(a, b00, ac0, 0, 0, 0);
            ac1 = __builtin_amdgcn_mfma_f32_16x16x32_bf16(a, b10, ac1, 0, 0, 0);
            ac2 = __builtin_amdgcn_mfma_f32_16x16x32_bf16(a, b20, ac2, 0, 0, 0);
            ac3 = __builtin_amdgcn_mfma_f32_16x16x32_bf16(a, b30, ac3, 0, 0, 0);
        }
        {
            float4 x0 = *(const float4*)(ap + 32);
            float4 x1 = *(const float4*)(ap + 36);
            bf16x8 a;
            a[0] = (short)f2b(x0.x); a[1] = (short)f2b(x0.y);
            a[2] = (short)f2b(x0.z); a[3] = (short)f2b(x0.w);
            a[4] = (short)f2b(x1.x); a[5] = (short)f2b(x1.y);
            a[6] = (short)f2b(x1.z); a[7] = (short)f2b(x1.w);
            ac0 = __builtin_amdgcn_mfma_f32_16x16x32_bf16(a, b01, ac0, 0, 0, 0);
            ac1 = __builtin_amdgcn_mfma_f32_16x16x32_bf16(a, b11, ac1, 0, 0, 0);
            ac2 = __builtin_amdgcn_mfma_f32_16x16x32_bf16(a, b21, ac2, 0, 0, 0);
            ac3 = __builtin_amdgcn_mfma_f32_16x16x32_bf16(a, b31, ac3, 0, 0, 0);
        }
        #pragma unroll
        for (int j = 0; j < 4; ++j) {
            size_t eg = eb + grp * 4 + j;
            float g = gamma[eg];
            float al = alpha[eg];
            int t = ety[eg];
            float4 v;
            v.x = ac0[j] * g; v.y = ac1[j] * g; v.z = ac2[j] * g; v.w = ac3[j] * g;
            *(float4*)&ew[eg * 64 + c4] = v;
            float w0 = (t == 0) ? al : 0.f, w1 = (t == 1) ? al : 0.f;
            float w2 = (t == 2) ? al : 0.f, w3 = (t == 3) ? al : 0.f;
            za0.x += w0 * v.x; za0.y += w0 * v.y; za0.z += w0 * v.z; za0.w += w0 * v.w;
            za1.x += w1 * v.x; za1.y += w1 * v.y; za1.z += w1 * v.z; za1.w += w1 * v.w;
            za2.x += w2 * v.x; za2.y += w2 * v.y; za2.z += w2 * v.z; za2.w += w2 * v.w;
            za3.x += w3 * v.x; za3.y += w3 * v.y; za3.z += w3 * v.z; za3.w += w3 * v.w;
        }
    }
    atomicAdd(&zl[0 * 64 + c4 + 0], za0.x); atomicAdd(&zl[0 * 64 + c4 + 1], za0.y);
    atomicAdd(&zl[0 * 64 + c4 + 2], za0.z); atomicAdd(&zl[0 * 64 + c4 + 3], za0.w);
    atomicAdd(&zl[1 * 64 + c4 + 0], za1.x); atomicAdd(&zl[1 * 64 + c4 + 1], za1.y);
    atomicAdd(&zl[1 * 64 + c4 + 2], za1.z); atomicAdd(&zl[1 * 64 + c4 + 3], za1.w);
    atomicAdd(&zl[2 * 64 + c4 + 0], za2.x); atomicAdd(&zl[2 * 64 + c4 + 1], za2.y);
    atomicAdd(&zl[2 * 64 + c4 + 2], za2.z); atomicAdd(&zl[2 * 64 + c4 + 3], za2.w);
    atomicAdd(&zl[3 * 64 + c4 + 0], za3.x); atomicAdd(&zl[3 * 64 + c4 + 1], za3.y);
    atomicAdd(&zl[3 * 64 + c4 + 2], za3.z); atomicAdd(&zl[3 * 64 + c4 + 3], za3.w);
    __syncthreads();
    zpart[(size_t)blockIdx.x * 256 + tid] = zl[tid];
}

// ---- K6b: fused zphi finalize: blocks [0,REDB) reduce zpart (middle dims);
//           blocks [REDB, REDB+128) accumulate z-parts from csrc/cdst. ----
__global__ __launch_bounds__(256) void k_zphi_fin(const float* __restrict__ zpart,
    const float* __restrict__ z, const float* __restrict__ csrc,
    const float* __restrict__ cdst, float* __restrict__ zphi)
{
    int tid = threadIdx.x;
    if (blockIdx.x < REDB) {
        float s = 0.f;
        int r0 = blockIdx.x * 25;
        for (int r = r0; r < r0 + 25; ++r)
            s += zpart[(size_t)r * 256 + tid];
        atomicAdd(&zphi[(tid >> 6) * 128 + 32 + (tid & 63)], s);
        return;
    }
    int bid = blockIdx.x - REDB;   // 0..127
    __shared__ float zl[256];
    zl[tid] = 0.f;
    __syncthreads();
    int d = tid & 31, ng = tid >> 5;
    float s0 = 0, s1 = 0, s2 = 0, s3 = 0, t0 = 0, t1 = 0, t2 = 0, t3 = 0;
    for (int n = bid * 8 + ng; n < NN; n += 128 * 8) {
        float zv = z[(size_t)n * 32 + d];
        float4 cs = *(const float4*)&csrc[n * 4];
        float4 cd = *(const float4*)&cdst[n * 4];
        s0 += cs.x * zv; s1 += cs.y * zv; s2 += cs.z * zv; s3 += cs.w * zv;
        t0 += cd.x * zv; t1 += cd.y * zv; t2 += cd.z * zv; t3 += cd.w * zv;
    }
    s0 += __shfl_xor(s0, 32); s1 += __shfl_xor(s1, 32);
    s2 += __shfl_xor(s2, 32); s3 += __shfl_xor(s3, 32);
    t0 += __shfl_xor(t0, 32); t1 += __shfl_xor(t1, 32);
    t2 += __shfl_xor(t2, 32); t3 += __shfl_xor(t3, 32);
    if ((tid & 63) < 32) {
        atomicAdd(&zl[0 * 32 + d], s0); atomicAdd(&zl[1 * 32 + d], s1);
        atomicAdd(&zl[2 * 32 + d], s2); atomicAdd(&zl[3 * 32 + d], s3);
        atomicAdd(&zl[128 + 0 * 32 + d], t0); atomicAdd(&zl[128 + 1 * 32 + d], t1);
        atomicAdd(&zl[128 + 2 * 32 + d], t2); atomicAdd(&zl[128 + 3 * 32 + d], t3);
    }
    __syncthreads();
    if (tid < 128) atomicAdd(&zphi[(tid >> 5) * 128 + (tid & 31)], zl[tid]);
    else atomicAdd(&zphi[((tid - 128) >> 5) * 128 + 96 + (tid & 31)], zl[tid]);
}

// ---- K7: beta = softmax(lrelu(zphi @ w_sem)) ----
__global__ __launch_bounds__(128) void k_beta(const float* __restrict__ zphi,
    const float* __restrict__ w_sem, float* __restrict__ beta)
{
    int tid = threadIdx.x;
    float w = w_sem[tid];
    float p0 = zphi[tid] * w, p1 = zphi[128 + tid] * w;
    float p2 = zphi[256 + tid] * w, p3 = zphi[384 + tid] * w;
    #pragma unroll
    for (int m = 32; m >= 1; m >>= 1) {
        p0 += __shfl_xor(p0, m); p1 += __shfl_xor(p1, m);
        p2 += __shfl_xor(p2, m); p3 += __shfl_xor(p3, m);
    }
    __shared__ float s[2][4];
    if ((tid & 63) == 0) {
        int w_ = tid >> 6;
        s[w_][0] = p0; s[w_][1] = p1; s[w_][2] = p2; s[w_][3] = p3;
    }
    __syncthreads();
    if (tid == 0) {
        float d0 = lrelu(s[0][0] + s[1][0]);
        float d1 = lrelu(s[0][1] + s[1][1]);
        float d2 = lrelu(s[0][2] + s[1][2]);
        float d3 = lrelu(s[0][3] + s[1][3]);
        float mx = fmaxf(fmaxf(d0, d1), fmaxf(d2, d3));
        float e0 = expf(d0 - mx), e1 = expf(d1 - mx), e2 = expf(d2 - mx), e3 = expf(d3 - mx);
        float inv = 1.f / (e0 + e1 + e2 + e3);
        beta[0] = e0 * inv; beta[1] = e1 * inv; beta[2] = e2 * inv; beta[3] = e3 * inv;
    }
}

// ---- K9: CSR scatter — one 32-lane group per node; w = alpha*beta[ety] inline ----
__global__ __launch_bounds__(256) void k_scatter(const int* __restrict__ offs,
    const int* __restrict__ eidx, const int* __restrict__ src,
    const float* __restrict__ alpha, const int* __restrict__ ety,
    const float* __restrict__ beta, const float* __restrict__ z,
    const float* __restrict__ ew, float* __restrict__ hbeta)
{
    int tid = threadIdx.x;
    int lane = tid & 31;
    int grp = tid >> 5;
    int n = blockIdx.x * 8 + grp;
    if (n >= NN) return;
    float b0 = beta[0], b1 = beta[1], b2 = beta[2], b3 = beta[3];
    int d0 = lane * 4;
    int beg = offs[n], end = offs[n + 1];
    float4 acc = make_float4(0, 0, 0, 0);
    float sumw = 0.f;
    int i = beg;
    for (; i + 2 <= end; i += 2) {
        int ea = eidx[i], eb = eidx[i + 1];
        int ta = ety[ea], tb = ety[eb];
        float wa = alpha[ea] * (ta == 0 ? b0 : ta == 1 ? b1 : ta == 2 ? b2 : b3);
        float wb = alpha[eb] * (tb == 0 ? b0 : tb == 1 ? b1 : tb == 2 ? b2 : b3);
        int sa = src[ea], sb = src[eb];
        sumw += wa + wb;
        if (lane < 24) {
            const float* pa = (lane < 8) ? &z[(size_t)sa * 32 + d0]
                                         : &ew[(size_t)ea * 64 + (d0 - 32)];
            const float* pb = (lane < 8) ? &z[(size_t)sb * 32 + d0]
                                         : &ew[(size_t)eb * 64 + (d0 - 32)];
            float4 ma = *(const float4*)pa;
            float4 mb = *(const float4*)pb;
            acc.x += wa * ma.x + wb * mb.x; acc.y += wa * ma.y + wb * mb.y;
            acc.z += wa * ma.z + wb * mb.z; acc.w += wa * ma.w + wb * mb.w;
        }
    }
    if (i < end) {
        int ea = eidx[i];
        int ta = ety[ea];
        float wa = alpha[ea] * (ta == 0 ? b0 : ta == 1 ? b1 : ta == 2 ? b2 : b3);
        int sa = src[ea];
        sumw += wa;
        if (lane < 24) {
            const float* pa = (lane < 8) ? &z[(size_t)sa * 32 + d0]
                                         : &ew[(size_t)ea * 64 + (d0 - 32)];
            float4 ma = *(const float4*)pa;
            acc.x += wa * ma.x; acc.y += wa * ma.y; acc.z += wa * ma.z; acc.w += wa * ma.w;
        }
    }
    if (lane >= 24) {
        float4 zd = *(const float4*)&z[(size_t)n * 32 + (d0 - 96)];
        acc.x = sumw * zd.x; acc.y = sumw * zd.y; acc.z = sumw * zd.z; acc.w = sumw * zd.w;
    }
    *(float4*)&hbeta[(size_t)n * 128 + d0] = acc;
}

// ---- K10: Z = hbeta @ W_fc2 ----
__global__ __launch_bounds__(256) void k_fc(const float* __restrict__ hb,
    const float* __restrict__ W, float* __restrict__ Z)
{
    __shared__ float hl[32 * 132];
    __shared__ float Wl[128 * 64];
    int tid = threadIdx.x;
    int nb = blockIdx.x * 32;
    for (int i = tid; i < 1024; i += 256) {
        int row = i >> 5, kc = (i & 31) * 4;
        float4 v = make_float4(0.f, 0.f, 0.f, 0.f);
        if (nb + row < NN) v = *(const float4*)&hb[(size_t)(nb + row) * 128 + kc];
        *(float4*)&hl[row * 132 + kc] = v;
    }
    for (int half = 0; half < 2; ++half) {
        __syncthreads();
        for (int i = tid; i < 2048; i += 256) {
            int k = i >> 4, c = (i & 15) * 4;
            *(float4*)&Wl[k * 64 + c] = *(const float4*)&W[(size_t)k * 128 + half * 64 + c];
        }
        __syncthreads();
        int node = tid >> 3;
        int c0 = (tid & 7) * 8;
        float acc[8] = {0, 0, 0, 0, 0, 0, 0, 0};
        #pragma unroll 4
        for (int k = 0; k < 128; ++k) {
            float a = hl[node * 132 + k];
            const float* wr = &Wl[k * 64 + c0];
            #pragma unroll
            for (int j = 0; j < 8; ++j) acc[j] += a * wr[j];
        }
        int n = nb + node;
        if (n < NN) {
            float4 o1, o2;
            o1.x = acc[0]; o1.y = acc[1]; o1.z = acc[2]; o1.w = acc[3];
            o2.x = acc[4]; o2.y = acc[5]; o2.z = acc[6]; o2.w = acc[7];
            *(float4*)&Z[(size_t)n * 128 + half * 64 + c0] = o1;
            *(float4*)&Z[(size_t)n * 128 + half * 64 + c0 + 4] = o2;
        }
    }
}

extern "C" void kernel_launch(void* const* d_in, const int* in_sizes, int n_in,
                              void* d_out, int out_size, void* d_ws, size_t ws_size,
                              hipStream_t stream)
{
    const float* nf     = (const float*)d_in[0];
    const float* ef     = (const float*)d_in[1];
    const int*   src    = (const int*)d_in[2];
    const int*   dst    = (const int*)d_in[3];
    const int*   ety    = (const int*)d_in[4];
    const float* W_n    = (const float*)d_in[5];
    const float* W_e    = (const float*)d_in[6];
    const float* w_eattn= (const float*)d_in[7];
    const float* w_attn = (const float*)d_in[8];
    const float* w_sem  = (const float*)d_in[9];
    const float* W_fc2  = (const float*)d_in[10];

    float* out = (float*)d_out;
    float* Z   = out;
    float* ew  = out + (size_t)NN * OUTD;

    float* ws    = (float*)d_ws;
    float* z     = ws + OFF_Z;
    float* a_src = ws + OFF_ASRC;
    float* b_src = ws + OFF_BSRC;
    float* b_dst = ws + OFF_BDST;
    float* zpart = ws + OFF_ZPART;
    float* c2    = ws + OFF_C2;
    float* s1x   = ws + OFF_S1X;
    float* gamma = ws + OFF_GAMMA;
    float* s2x   = ws + OFF_S2X;
    float* alpha = ws + OFF_S1X;     // alias: s1x dead after k_g2ex
    float* den1  = ws + OFF_DEN1;
    float* den2  = ws + OFF_DEN2;
    float* zphi  = ws + OFF_ZPHI;
    float* beta  = ws + OFF_BETA;
    float* csrc  = ws + OFF_CSRC;
    float* cdst  = ws + OFF_CDST;
    int* deg     = (int*)(ws + OFF_DEG);
    int* offs    = (int*)(ws + OFF_OFFS);
    int* cursor  = (int*)(ws + OFF_CURSOR);
    int* eidx    = (int*)(ws + OFF_EIDX);
    float* hbeta = ws + OFF_HBETA;
    float* u1    = ws + OFF_U1;
    float* u2    = ws + OFF_U2;
    unsigned short* Wt = (unsigned short*)(ws + OFF_WT);

    k_zero<<<270, 256, 0, stream>>>((float4*)(ws + OFF_DEN1));
    k_node<<<NN / 8, 256, 0, stream>>>(nf, W_n, w_eattn, w_attn, z, a_src, b_src, b_dst);
    k_prep<<<1, 256, 0, stream>>>(W_e, w_eattn, w_attn, u1, u2, Wt);
    k_c12s1<<<2048, 256, 0, stream>>>(ef, u1, u2, a_src, src, dst, c2, s1x, den1, deg);
    k_scan<<<1, 1024, 0, stream>>>(deg, offs, cursor);
    int gE = (NE + 255) / 256;
    k_g2ex<<<gE, 256, 0, stream>>>(src, dst, s1x, den1, c2, b_src, b_dst, gamma, s2x, den2, cursor, eidx);
    k_alpha<<<gE, 256, 0, stream>>>(src, dst, ety, s2x, den2, alpha, csrc, cdst);
    k_edge_mfma<<<EGRID, 256, 0, stream>>>(ef, Wt, gamma, alpha, ety, ew, zpart);
    k_zphi_fin<<<REDB + 128, 256, 0, stream>>>(zpart, z, csrc, cdst, zphi);
    k_beta<<<1, 128, 0, stream>>>(zphi, w_sem, beta);
    k_scatter<<<(NN + 7) / 8, 256, 0, stream>>>(offs, eidx, src, alpha, ety, beta, z, ew, hbeta);
    k_fc<<<(NN + 31) / 32, 256, 0, stream>>>(hbeta, W_fc2, Z);
}

// Round 21
// 327.097 us; speedup vs baseline: 1.0454x; 1.0454x over previous
//
#include <hip/hip_runtime.h>

#define NN 25000
#define NE 400000
#define TT 4
#define NO 32
#define EO 64
#define DD 128
#define OUTD 128
#define EGRID 1250   // 6250 tiles / 1250 blocks = exactly 5 tiles/block
#define REDB (EGRID / 25)   // 50 reduction blocks in k_zphi_fin

// ws offsets (in floats) — ws_size ~450 MB (measured via harness poison fill)
#define OFF_Z      0
#define OFF_ASRC   800000
#define OFF_BSRC   825000
#define OFF_BDST   850000
#define OFF_ZPART  875000     // 1250*256 = 320000 floats
#define OFF_C2     1400000
#define OFF_S1X    1800000    // aliased by alpha after k_g2ex
#define OFF_GAMMA  2200000
#define OFF_S2X    2600000
// ---- zero zone [OFF_DEN1, OFF_OFFS) ----
#define OFF_DEN1   3000000
#define OFF_DEN2   3025000
#define OFF_ZPHI   3050000
#define OFF_BETA   3050512
#define OFF_CSRC   3051000
#define OFF_CDST   3151000
#define OFF_DEG    3251000
// ---- end zero zone ----
#define OFF_OFFS   3276000
#define OFF_CURSOR 3301004
#define OFF_EIDX   3326004
#define OFF_HBETA  3726008
#define OFF_U1     6926008
#define OFF_U2     6926072
#define OFF_WT     6926136    // 64*64 bf16 = 2048 floats
#define OFF_POSS   6928184    // 400000 ints: e -> CSR position
#define OFF_SRCC   7328184    // 400000 ints: CSR-ordered src
#define OFF_WCSR   7728184    // 400000 floats: CSR-ordered w
#define WS_FLOATS  8128184

#define ZERO_N4    ((OFF_OFFS - OFF_DEN1) / 4)   // 69000 float4s

typedef __attribute__((ext_vector_type(8))) short bf16x8;
typedef __attribute__((ext_vector_type(4))) float f32x4;

__device__ __forceinline__ float lrelu(float x) { return x > 0.f ? x : 0.01f * x; }

__device__ __forceinline__ unsigned short f2b(float x) {
    unsigned u = __float_as_uint(x);
    u += 0x7FFFu + ((u >> 16) & 1u);   // RNE
    return (unsigned short)(u >> 16);
}

// ---- K0: fast zero of the accumulator zone ----
__global__ __launch_bounds__(256) void k_zero(float4* __restrict__ p)
{
    int i = blockIdx.x * 256 + threadIdx.x;
    int stride = gridDim.x * 256;
    for (; i < ZERO_N4; i += stride)
        p[i] = make_float4(0.f, 0.f, 0.f, 0.f);
}

// ---- K1: z = nf @ W_n ; per-node scalars a_src, b_src, b_dst ----
__global__ __launch_bounds__(256) void k_node(const float* __restrict__ nf,
    const float* __restrict__ W_n, const float* __restrict__ w_eattn,
    const float* __restrict__ w_attn, float* __restrict__ z,
    float* __restrict__ a_src, float* __restrict__ b_src, float* __restrict__ b_dst)
{
    __shared__ float Wl[128 * 32];
    __shared__ float nl[8 * 128];
    int tid = threadIdx.x;
    for (int i = tid; i < 128 * 32 / 4; i += 256)
        ((float4*)Wl)[i] = ((const float4*)W_n)[i];
    int nb = blockIdx.x * 8;
    ((float4*)nl)[tid] = ((const float4*)(nf + (size_t)nb * 128))[tid];
    __syncthreads();
    int node = tid >> 5;
    int col = tid & 31;
    float acc = 0.f;
    #pragma unroll 8
    for (int k = 0; k < 128; ++k)
        acc += nl[node * 128 + k] * Wl[k * 32 + col];
    int n = nb + node;
    z[(size_t)n * 32 + col] = acc;
    float va = acc * w_eattn[64 + col];
    float vb = acc * w_attn[col];
    float vc = acc * w_attn[96 + col];
    #pragma unroll
    for (int m = 16; m >= 1; m >>= 1) {
        va += __shfl_xor(va, m);
        vb += __shfl_xor(vb, m);
        vc += __shfl_xor(vc, m);
    }
    if (col == 0) { a_src[n] = va; b_src[n] = vb; b_dst[n] = vc; }
}

// ---- K1b: u1 = W_e @ w_eattn[0:64], u2 = W_e @ w_attn[32:96];
//           Wt[c][k] = bf16(W_e[k][c]) (transposed bf16 copy) ----
__global__ void k_prep(const float* __restrict__ W_e, const float* __restrict__ w_eattn,
                       const float* __restrict__ w_attn, float* __restrict__ u1,
                       float* __restrict__ u2, unsigned short* __restrict__ Wt)
{
    int tid = threadIdx.x;
    if (tid < 64) {
        float s1 = 0.f, s2 = 0.f;
        for (int o = 0; o < 64; ++o) {
            float w = W_e[tid * 64 + o];
            s1 += w * w_eattn[o];
            s2 += w * w_attn[32 + o];
        }
        u1[tid] = s1; u2[tid] = s2;
    }
    for (int i = tid; i < 4096; i += 256) {
        int c = i >> 6, k = i & 63;
        Wt[i] = f2b(W_e[k * 64 + c]);
    }
}

// ---- K2: stream ef: s1x=exp(lrelu(ef·u1+a_src)), c2=ef·u2; den1; deg ----
__global__ __launch_bounds__(256) void k_c12s1(const float* __restrict__ ef,
    const float* __restrict__ u1, const float* __restrict__ u2,
    const float* __restrict__ a_src, const int* __restrict__ src, const int* __restrict__ dst,
    float* __restrict__ c2, float* __restrict__ s1x, float* __restrict__ den1, int* __restrict__ deg)
{
    int lane = threadIdx.x & 15, grp = threadIdx.x >> 4;
    float4 v1 = *(const float4*)&u1[lane * 4];
    float4 v2 = *(const float4*)&u2[lane * 4];
    int estep = gridDim.x * 16;
    for (int e = blockIdx.x * 16 + grp; e < NE; e += estep) {
        float4 x = *(const float4*)&ef[(size_t)e * 64 + lane * 4];
        float d1 = x.x * v1.x + x.y * v1.y + x.z * v1.z + x.w * v1.w;
        float d2 = x.x * v2.x + x.y * v2.y + x.z * v2.z + x.w * v2.w;
        #pragma unroll
        for (int m = 8; m >= 1; m >>= 1) {
            d1 += __shfl_xor(d1, m);
            d2 += __shfl_xor(d2, m);
        }
        if (lane == 0) {
            int s = src[e];
            float ex = expf(lrelu(d1 + a_src[s]));
            s1x[e] = ex;
            c2[e] = d2;
            atomicAdd(&den1[s], ex);
            atomicAdd(&deg[dst[e]], 1);
        }
    }
}

// ---- K4: exclusive prefix scan of deg -> offs, cursor (single block, shfl) ----
__global__ __launch_bounds__(1024) void k_scan(const int* __restrict__ deg,
    int* __restrict__ offs, int* __restrict__ cursor)
{
    __shared__ int wsum[16];
    __shared__ int carry_s;
    int tid = threadIdx.x;
    int lane = tid & 63, wid = tid >> 6;
    if (tid == 0) carry_s = 0;
    __syncthreads();
    for (int base = 0; base < NN; base += 1024) {
        int idx = base + tid;
        int v = (idx < NN) ? deg[idx] : 0;
        int x = v;
        #pragma unroll
        for (int off = 1; off < 64; off <<= 1) {
            int t = __shfl_up(x, off);
            if (lane >= off) x += t;
        }
        if (lane == 63) wsum[wid] = x;
        __syncthreads();
        if (wid == 0) {
            int s = (lane < 16) ? wsum[lane] : 0;
            #pragma unroll
            for (int off = 1; off < 16; off <<= 1) {
                int t = __shfl_up(s, off);
                if (lane >= off) s += t;
            }
            if (lane < 16) wsum[lane] = s;
        }
        __syncthreads();
        int wbase = (wid > 0) ? wsum[wid - 1] : 0;
        int incl = x + wbase;
        int carry = carry_s;
        if (idx < NN) {
            int excl = carry + incl - v;
            offs[idx] = excl;
            cursor[idx] = excl;
        }
        __syncthreads();
        if (tid == 1023) carry_s = carry + incl;
        __syncthreads();
    }
    if (tid == 0) offs[NN] = carry_s;
}

// ---- K5: gamma; ex2 = exp(lrelu(...)); den2 +=; CSR fill (eidx, src_csr, poss) ----
__global__ void k_g2ex(const int* __restrict__ src, const int* __restrict__ dst,
    const float* __restrict__ s1x, const float* __restrict__ den1,
    const float* __restrict__ c2, const float* __restrict__ b_src, const float* __restrict__ b_dst,
    float* __restrict__ gamma, float* __restrict__ s2x, float* __restrict__ den2,
    int* __restrict__ cursor, int* __restrict__ eidx,
    int* __restrict__ poss, int* __restrict__ src_csr)
{
    int e = blockIdx.x * 256 + threadIdx.x;
    if (e >= NE) return;
    int s = src[e], t = dst[e];
    float g = s1x[e] / den1[s];
    gamma[e] = g;
    float ex = expf(lrelu(b_src[s] + g * c2[e] + b_dst[t]));
    s2x[e] = ex;
    atomicAdd(&den2[t], ex);
    int pos = atomicAdd(&cursor[t], 1);
    eidx[pos] = e;
    poss[e] = pos;
    src_csr[pos] = s;
}

// ---- K5b: alpha[e] = s2x/den2[dst]; csrc/cdst per-node-type coefficients ----
__global__ void k_alpha(const int* __restrict__ src, const int* __restrict__ dst,
    const int* __restrict__ ety, const float* __restrict__ s2x, const float* __restrict__ den2,
    float* __restrict__ alpha, float* __restrict__ csrc, float* __restrict__ cdst)
{
    int e = blockIdx.x * 256 + threadIdx.x;
    if (e >= NE) return;
    int t = dst[e];
    int ty = ety[e];
    float al = s2x[e] / den2[t];
    alpha[e] = al;
    atomicAdd(&csrc[src[e] * 4 + ty], al);
    atomicAdd(&cdst[t * 4 + ty], al);
}

// ---- K6: MFMA GEMM (bf16 in, f32 acc) + gamma-scale + e_w write + zphi acc. ----
__global__ __launch_bounds__(256) void k_edge_mfma(const float* __restrict__ ef,
    const unsigned short* __restrict__ Wt, const float* __restrict__ gamma,
    const float* __restrict__ alpha, const int* __restrict__ ety,
    float* __restrict__ ew, float* __restrict__ zpart)
{
    __shared__ float zl[256];
    int tid = threadIdx.x;
    zl[tid] = 0.f;
    int wv = tid >> 6, lane = tid & 63;
    int row16 = lane & 15, grp = lane >> 4;
    int c4 = row16 * 4;
    bf16x8 b00 = *(const bf16x8*)&Wt[(c4 + 0) * 64 + 0  + grp * 8];
    bf16x8 b01 = *(const bf16x8*)&Wt[(c4 + 0) * 64 + 32 + grp * 8];
    bf16x8 b10 = *(const bf16x8*)&Wt[(c4 + 1) * 64 + 0  + grp * 8];
    bf16x8 b11 = *(const bf16x8*)&Wt[(c4 + 1) * 64 + 32 + grp * 8];
    bf16x8 b20 = *(const bf16x8*)&Wt[(c4 + 2) * 64 + 0  + grp * 8];
    bf16x8 b21 = *(const bf16x8*)&Wt[(c4 + 2) * 64 + 32 + grp * 8];
    bf16x8 b30 = *(const bf16x8*)&Wt[(c4 + 3) * 64 + 0  + grp * 8];
    bf16x8 b31 = *(const bf16x8*)&Wt[(c4 + 3) * 64 + 32 + grp * 8];
    __syncthreads();
    float4 za0 = make_float4(0, 0, 0, 0), za1 = za0, za2 = za0, za3 = za0;
    for (int tile = blockIdx.x; tile < NE / 64; tile += EGRID) {
        size_t eb = (size_t)tile * 64 + wv * 16;
        f32x4 ac0 = {0.f, 0.f, 0.f, 0.f}, ac1 = ac0, ac2 = ac0, ac3 = ac0;
        const float* ap = &ef[(eb + row16) * 64 + grp * 8];
        {
            float4 x0 = *(const float4*)ap;
            float4 x1 = *(const float4*)(ap + 4);
            bf16x8 a;
            a[0] = (short)f2b(x0.x); a[1] = (short)f2b(x0.y);
            a[2] = (short)f2b(x0.z); a[3] = (short)f2b(x0.w);
            a[4] = (short)f2b(x1.x); a[5] = (short)f2b(x1.y);
            a[6] = (short)f2b(x1.z); a[7] = (short)f2b(x1.w);
            ac0 = __builtin_amdgcn_mfma_f32_16x16x32_bf16(a, b00, ac0, 0, 0, 0);
            ac1 = __builtin_amdgcn_mfma_f32_16x16x32_bf16(a, b10, ac1, 0, 0, 0);
            ac2 = __builtin_amdgcn_mfma_f32_16x16x32_bf16(a, b20, ac2, 0, 0, 0);
            ac3 = __builtin_amdgcn_mfma_f32_16x16x32_bf16(a, b30, ac3, 0, 0, 0);
        }
        {
            float4 x0 = *(const float4*)(ap + 32);
            float4 x1 = *(const float4*)(ap + 36);
            bf16x8 a;
            a[0] = (short)f2b(x0.x); a[1] = (short)f2b(x0.y);
            a[2] = (short)f2b(x0.z); a[3] = (short)f2b(x0.w);
            a[4] = (short)f2b(x1.x); a[5] = (short)f2b(x1.y);
            a[6] = (short)f2b(x1.z); a[7] = (short)f2b(x1.w);
            ac0 = __builtin_amdgcn_mfma_f32_16x16x32_bf16(a, b01, ac0, 0, 0, 0);
            ac1 = __builtin_amdgcn_mfma_f32_16x16x32_bf16(a, b11, ac1, 0, 0, 0);
            ac2 = __builtin_amdgcn_mfma_f32_16x16x32_bf16(a, b21, ac2, 0, 0, 0);
            ac3 = __builtin_amdgcn_mfma_f32_16x16x32_bf16(a, b31, ac3, 0, 0, 0);
        }
        #pragma unroll
        for (int j = 0; j < 4; ++j) {
            size_t eg = eb + grp * 4 + j;
            float g = gamma[eg];
            float al = alpha[eg];
            int t = ety[eg];
            float4 v;
            v.x = ac0[j] * g; v.y = ac1[j] * g; v.z = ac2[j] * g; v.w = ac3[j] * g;
            *(float4*)&ew[eg * 64 + c4] = v;
            float w0 = (t == 0) ? al : 0.f, w1 = (t == 1) ? al : 0.f;
            float w2 = (t == 2) ? al : 0.f, w3 = (t == 3) ? al : 0.f;
            za0.x += w0 * v.x; za0.y += w0 * v.y; za0.z += w0 * v.z; za0.w += w0 * v.w;
            za1.x += w1 * v.x; za1.y += w1 * v.y; za1.z += w1 * v.z; za1.w += w1 * v.w;
            za2.x += w2 * v.x; za2.y += w2 * v.y; za2.z += w2 * v.z; za2.w += w2 * v.w;
            za3.x += w3 * v.x; za3.y += w3 * v.y; za3.z += w3 * v.z; za3.w += w3 * v.w;
        }
    }
    atomicAdd(&zl[0 * 64 + c4 + 0], za0.x); atomicAdd(&zl[0 * 64 + c4 + 1], za0.y);
    atomicAdd(&zl[0 * 64 + c4 + 2], za0.z); atomicAdd(&zl[0 * 64 + c4 + 3], za0.w);
    atomicAdd(&zl[1 * 64 + c4 + 0], za1.x); atomicAdd(&zl[1 * 64 + c4 + 1], za1.y);
    atomicAdd(&zl[1 * 64 + c4 + 2], za1.z); atomicAdd(&zl[1 * 64 + c4 + 3], za1.w);
    atomicAdd(&zl[2 * 64 + c4 + 0], za2.x); atomicAdd(&zl[2 * 64 + c4 + 1], za2.y);
    atomicAdd(&zl[2 * 64 + c4 + 2], za2.z); atomicAdd(&zl[2 * 64 + c4 + 3], za2.w);
    atomicAdd(&zl[3 * 64 + c4 + 0], za3.x); atomicAdd(&zl[3 * 64 + c4 + 1], za3.y);
    atomicAdd(&zl[3 * 64 + c4 + 2], za3.z); atomicAdd(&zl[3 * 64 + c4 + 3], za3.w);
    __syncthreads();
    zpart[(size_t)blockIdx.x * 256 + tid] = zl[tid];
}

// ---- K6b: fused zphi finalize: blocks [0,REDB) reduce zpart (middle dims);
//           blocks [REDB, REDB+128) accumulate z-parts from csrc/cdst. ----
__global__ __launch_bounds__(256) void k_zphi_fin(const float* __restrict__ zpart,
    const float* __restrict__ z, const float* __restrict__ csrc,
    const float* __restrict__ cdst, float* __restrict__ zphi)
{
    int tid = threadIdx.x;
    if (blockIdx.x < REDB) {
        float s = 0.f;
        int r0 = blockIdx.x * 25;
        for (int r = r0; r < r0 + 25; ++r)
            s += zpart[(size_t)r * 256 + tid];
        atomicAdd(&zphi[(tid >> 6) * 128 + 32 + (tid & 63)], s);
        return;
    }
    int bid = blockIdx.x - REDB;   // 0..127
    __shared__ float zl[256];
    zl[tid] = 0.f;
    __syncthreads();
    int d = tid & 31, ng = tid >> 5;
    float s0 = 0, s1 = 0, s2 = 0, s3 = 0, t0 = 0, t1 = 0, t2 = 0, t3 = 0;
    for (int n = bid * 8 + ng; n < NN; n += 128 * 8) {
        float zv = z[(size_t)n * 32 + d];
        float4 cs = *(const float4*)&csrc[n * 4];
        float4 cd = *(const float4*)&cdst[n * 4];
        s0 += cs.x * zv; s1 += cs.y * zv; s2 += cs.z * zv; s3 += cs.w * zv;
        t0 += cd.x * zv; t1 += cd.y * zv; t2 += cd.z * zv; t3 += cd.w * zv;
    }
    s0 += __shfl_xor(s0, 32); s1 += __shfl_xor(s1, 32);
    s2 += __shfl_xor(s2, 32); s3 += __shfl_xor(s3, 32);
    t0 += __shfl_xor(t0, 32); t1 += __shfl_xor(t1, 32);
    t2 += __shfl_xor(t2, 32); t3 += __shfl_xor(t3, 32);
    if ((tid & 63) < 32) {
        atomicAdd(&zl[0 * 32 + d], s0); atomicAdd(&zl[1 * 32 + d], s1);
        atomicAdd(&zl[2 * 32 + d], s2); atomicAdd(&zl[3 * 32 + d], s3);
        atomicAdd(&zl[128 + 0 * 32 + d], t0); atomicAdd(&zl[128 + 1 * 32 + d], t1);
        atomicAdd(&zl[128 + 2 * 32 + d], t2); atomicAdd(&zl[128 + 3 * 32 + d], t3);
    }
    __syncthreads();
    if (tid < 128) atomicAdd(&zphi[(tid >> 5) * 128 + (tid & 31)], zl[tid]);
    else atomicAdd(&zphi[((tid - 128) >> 5) * 128 + 96 + (tid & 31)], zl[tid]);
}

// ---- K7: beta = softmax(lrelu(zphi @ w_sem)) ----
__global__ __launch_bounds__(128) void k_beta(const float* __restrict__ zphi,
    const float* __restrict__ w_sem, float* __restrict__ beta)
{
    int tid = threadIdx.x;
    float w = w_sem[tid];
    float p0 = zphi[tid] * w, p1 = zphi[128 + tid] * w;
    float p2 = zphi[256 + tid] * w, p3 = zphi[384 + tid] * w;
    #pragma unroll
    for (int m = 32; m >= 1; m >>= 1) {
        p0 += __shfl_xor(p0, m); p1 += __shfl_xor(p1, m);
        p2 += __shfl_xor(p2, m); p3 += __shfl_xor(p3, m);
    }
    __shared__ float s[2][4];
    if ((tid & 63) == 0) {
        int w_ = tid >> 6;
        s[w_][0] = p0; s[w_][1] = p1; s[w_][2] = p2; s[w_][3] = p3;
    }
    __syncthreads();
    if (tid == 0) {
        float d0 = lrelu(s[0][0] + s[1][0]);
        float d1 = lrelu(s[0][1] + s[1][1]);
        float d2 = lrelu(s[0][2] + s[1][2]);
        float d3 = lrelu(s[0][3] + s[1][3]);
        float mx = fmaxf(fmaxf(d0, d1), fmaxf(d2, d3));
        float e0 = expf(d0 - mx), e1 = expf(d1 - mx), e2 = expf(d2 - mx), e3 = expf(d3 - mx);
        float inv = 1.f / (e0 + e1 + e2 + e3);
        beta[0] = e0 * inv; beta[1] = e1 * inv; beta[2] = e2 * inv; beta[3] = e3 * inv;
    }
}

// ---- K8: w_csr[poss[e]] = alpha[e] * beta[ety[e]] (CSR-ordered weight) ----
__global__ void k_walpha(const float* __restrict__ alpha, const int* __restrict__ ety,
                         const float* __restrict__ beta, const int* __restrict__ poss,
                         float* __restrict__ w_csr)
{
    int e = blockIdx.x * 256 + threadIdx.x;
    if (e >= NE) return;
    w_csr[poss[e]] = alpha[e] * beta[ety[e]];
}

// ---- K9: CSR scatter — sequential scalars (w_csr, src_csr); random only on
//          the unavoidable ew/z float4 gathers. ----
__global__ __launch_bounds__(256) void k_scatter(const int* __restrict__ offs,
    const int* __restrict__ eidx, const int* __restrict__ src_csr,
    const float* __restrict__ w_csr, const float* __restrict__ z,
    const float* __restrict__ ew, float* __restrict__ hbeta)
{
    int tid = threadIdx.x;
    int lane = tid & 31;
    int grp = tid >> 5;
    int n = blockIdx.x * 8 + grp;
    if (n >= NN) return;
    int d0 = lane * 4;
    int beg = offs[n], end = offs[n + 1];
    float4 acc = make_float4(0, 0, 0, 0);
    float sumw = 0.f;
    int i = beg;
    for (; i + 2 <= end; i += 2) {
        int ea = eidx[i], eb = eidx[i + 1];
        float wa = w_csr[i], wb = w_csr[i + 1];
        int sa = src_csr[i], sb = src_csr[i + 1];
        sumw += wa + wb;
        if (lane < 24) {
            const float* pa = (lane < 8) ? &z[(size_t)sa * 32 + d0]
                                         : &ew[(size_t)ea * 64 + (d0 - 32)];
            const float* pb = (lane < 8) ? &z[(size_t)sb * 32 + d0]
                                         : &ew[(size_t)eb * 64 + (d0 - 32)];
            float4 ma = *(const float4*)pa;
            float4 mb = *(const float4*)pb;
            acc.x += wa * ma.x + wb * mb.x; acc.y += wa * ma.y + wb * mb.y;
            acc.z += wa * ma.z + wb * mb.z; acc.w += wa * ma.w + wb * mb.w;
        }
    }
    if (i < end) {
        int ea = eidx[i];
        float wa = w_csr[i];
        int sa = src_csr[i];
        sumw += wa;
        if (lane < 24) {
            const float* pa = (lane < 8) ? &z[(size_t)sa * 32 + d0]
                                         : &ew[(size_t)ea * 64 + (d0 - 32)];
            float4 ma = *(const float4*)pa;
            acc.x += wa * ma.x; acc.y += wa * ma.y; acc.z += wa * ma.z; acc.w += wa * ma.w;
        }
    }
    if (lane >= 24) {
        float4 zd = *(const float4*)&z[(size_t)n * 32 + (d0 - 96)];
        acc.x = sumw * zd.x; acc.y = sumw * zd.y; acc.z = sumw * zd.z; acc.w = sumw * zd.w;
    }
    *(float4*)&hbeta[(size_t)n * 128 + d0] = acc;
}

// ---- K10: Z = hbeta @ W_fc2 ----
__global__ __launch_bounds__(256) void k_fc(const float* __restrict__ hb,
    const float* __restrict__ W, float* __restrict__ Z)
{
    __shared__ float hl[32 * 132];
    __shared__ float Wl[128 * 64];
    int tid = threadIdx.x;
    int nb = blockIdx.x * 32;
    for (int i = tid; i < 1024; i += 256) {
        int row = i >> 5, kc = (i & 31) * 4;
        float4 v = make_float4(0.f, 0.f, 0.f, 0.f);
        if (nb + row < NN) v = *(const float4*)&hb[(size_t)(nb + row) * 128 + kc];
        *(float4*)&hl[row * 132 + kc] = v;
    }
    for (int half = 0; half < 2; ++half) {
        __syncthreads();
        for (int i = tid; i < 2048; i += 256) {
            int k = i >> 4, c = (i & 15) * 4;
            *(float4*)&Wl[k * 64 + c] = *(const float4*)&W[(size_t)k * 128 + half * 64 + c];
        }
        __syncthreads();
        int node = tid >> 3;
        int c0 = (tid & 7) * 8;
        float acc[8] = {0, 0, 0, 0, 0, 0, 0, 0};
        #pragma unroll 4
        for (int k = 0; k < 128; ++k) {
            float a = hl[node * 132 + k];
            const float* wr = &Wl[k * 64 + c0];
            #pragma unroll
            for (int j = 0; j < 8; ++j) acc[j] += a * wr[j];
        }
        int n = nb + node;
        if (n < NN) {
            float4 o1, o2;
            o1.x = acc[0]; o1.y = acc[1]; o1.z = acc[2]; o1.w = acc[3];
            o2.x = acc[4]; o2.y = acc[5]; o2.z = acc[6]; o2.w = acc[7];
            *(float4*)&Z[(size_t)n * 128 + half * 64 + c0] = o1;
            *(float4*)&Z[(size_t)n * 128 + half * 64 + c0 + 4] = o2;
        }
    }
}

extern "C" void kernel_launch(void* const* d_in, const int* in_sizes, int n_in,
                              void* d_out, int out_size, void* d_ws, size_t ws_size,
                              hipStream_t stream)
{
    const float* nf     = (const float*)d_in[0];
    const float* ef     = (const float*)d_in[1];
    const int*   src    = (const int*)d_in[2];
    const int*   dst    = (const int*)d_in[3];
    const int*   ety    = (const int*)d_in[4];
    const float* W_n    = (const float*)d_in[5];
    const float* W_e    = (const float*)d_in[6];
    const float* w_eattn= (const float*)d_in[7];
    const float* w_attn = (const float*)d_in[8];
    const float* w_sem  = (const float*)d_in[9];
    const float* W_fc2  = (const float*)d_in[10];

    float* out = (float*)d_out;
    float* Z   = out;
    float* ew  = out + (size_t)NN * OUTD;

    float* ws    = (float*)d_ws;
    float* z     = ws + OFF_Z;
    float* a_src = ws + OFF_ASRC;
    float* b_src = ws + OFF_BSRC;
    float* b_dst = ws + OFF_BDST;
    float* zpart = ws + OFF_ZPART;
    float* c2    = ws + OFF_C2;
    float* s1x   = ws + OFF_S1X;
    float* gamma = ws + OFF_GAMMA;
    float* s2x   = ws + OFF_S2X;
    float* alpha = ws + OFF_S1X;     // alias: s1x dead after k_g2ex
    float* den1  = ws + OFF_DEN1;
    float* den2  = ws + OFF_DEN2;
    float* zphi  = ws + OFF_ZPHI;
    float* beta  = ws + OFF_BETA;
    float* csrc  = ws + OFF_CSRC;
    float* cdst  = ws + OFF_CDST;
    int* deg     = (int*)(ws + OFF_DEG);
    int* offs    = (int*)(ws + OFF_OFFS);
    int* cursor  = (int*)(ws + OFF_CURSOR);
    int* eidx    = (int*)(ws + OFF_EIDX);
    float* hbeta = ws + OFF_HBETA;
    float* u1    = ws + OFF_U1;
    float* u2    = ws + OFF_U2;
    unsigned short* Wt = (unsigned short*)(ws + OFF_WT);
    int* poss    = (int*)(ws + OFF_POSS);
    int* src_csr = (int*)(ws + OFF_SRCC);
    float* w_csr = ws + OFF_WCSR;

    k_zero<<<270, 256, 0, stream>>>((float4*)(ws + OFF_DEN1));
    k_node<<<NN / 8, 256, 0, stream>>>(nf, W_n, w_eattn, w_attn, z, a_src, b_src, b_dst);
    k_prep<<<1, 256, 0, stream>>>(W_e, w_eattn, w_attn, u1, u2, Wt);
    k_c12s1<<<2048, 256, 0, stream>>>(ef, u1, u2, a_src, src, dst, c2, s1x, den1, deg);
    k_scan<<<1, 1024, 0, stream>>>(deg, offs, cursor);
    int gE = (NE + 255) / 256;
    k_g2ex<<<gE, 256, 0, stream>>>(src, dst, s1x, den1, c2, b_src, b_dst, gamma, s2x, den2, cursor, eidx, poss, src_csr);
    k_alpha<<<gE, 256, 0, stream>>>(src, dst, ety, s2x, den2, alpha, csrc, cdst);
    k_edge_mfma<<<EGRID, 256, 0, stream>>>(ef, Wt, gamma, alpha, ety, ew, zpart);
    k_zphi_fin<<<REDB + 128, 256, 0, stream>>>(zpart, z, csrc, cdst, zphi);
    k_beta<<<1, 128, 0, stream>>>(zphi, w_sem, beta);
    k_walpha<<<gE, 256, 0, stream>>>(alpha, ety, beta, poss, w_csr);
    k_scatter<<<(NN + 7) / 8, 256, 0, stream>>>(offs, eidx, src_csr, w_csr, z, ew, hbeta);
    k_fc<<<(NN + 31) / 32, 256, 0, stream>>>(hbeta, W_fc2, Z);
}